// Round 4
// baseline (379.536 us; speedup 1.0000x reference)
//
#include <hip/hip_runtime.h>
#include <math.h>

// Problem constants (fixed by setup_inputs)
constexpr int Bsz   = 64;
constexpr int Mmel  = 80;
constexpr int Tout  = 2000;
constexpr int Tin   = 400;
constexpr int MEL_N  = Bsz * Mmel * Tout;   // 10,240,000
constexpr int GATE_N = Bsz * Tout;          // 128,000
constexpr int TIN4   = Tin / 4;             // 100 float4 per row

constexpr float ATT_W = 0.1f;
constexpr float GA_W  = 0.1f;
// exp(-d^2 * 3.125) == exp2(d^2 * -3.125*log2(e))
constexpr float NEG_C = -3.125f * 1.44269504088896340736f;

constexpr int NBLK   = 2048;
constexpr int NTHR   = 256;
constexpr int NWAVES = NBLK * NTHR / 64;    // 8192
constexpr int AWAVES = 8000;                // waves doing mel+align chunks
constexpr int WPB    = 125;                 // align: waves per batch (125*16 = 2000 rows)
constexpr int RPW    = 16;                  // align: rows per wave
constexpr int MEL4PW = 320;                 // mel: float4 per wave (8000*320 = 2.56M exactly)

__device__ __forceinline__ float wave_reduce(float v) {
    #pragma unroll
    for (int off = 32; off > 0; off >>= 1)
        v += __shfl_down(v, off, 64);
    return v;
}

__device__ __forceinline__ double wave_reduce_d(double v) {
    #pragma unroll
    for (int off = 32; off > 0; off >>= 1)
        v += __shfl_down(v, off, 64);
    return v;
}

__global__ __launch_bounds__(NTHR, 4) void loss_main(
    const float* __restrict__ mel_out,
    const float* __restrict__ mel_post,
    const float* __restrict__ gate_out,
    const float* __restrict__ align,
    const float* __restrict__ mel_tgt,
    const float* __restrict__ gate_tgt,
    const int*   __restrict__ in_len,
    const int*   __restrict__ out_len,
    float4* __restrict__ partials)          // partials[blockIdx] = {mel, gate, att, ga}
{
    __shared__ float s_ilf[Bsz];
    __shared__ float s_olf[Bsz];
    __shared__ float s_sc[Bsz];
    if (threadIdx.x < Bsz) {
        const float il = (float)in_len[threadIdx.x];
        const float ol = (float)out_len[threadIdx.x];
        s_ilf[threadIdx.x] = il;
        s_olf[threadIdx.x] = ol;
        s_sc[threadIdx.x]  = ol / il;
    }
    __syncthreads();

    const int wv   = blockIdx.x * (NTHR / 64) + (threadIdx.x >> 6);
    const int lane = threadIdx.x & 63;

    float mel_s = 0.f, gate_s = 0.f, att_s = 0.f, ga_s = 0.f;

    // ---- Gate BCE-with-logits (tiny: 0.5 MB) ----
    {
        const float4* x4 = (const float4*)gate_out;
        const float4* z4 = (const float4*)gate_tgt;
        const int tid    = blockIdx.x * blockDim.x + threadIdx.x;
        const int stride = gridDim.x * blockDim.x;
        const int n4 = GATE_N / 4;
        for (int i = tid; i < n4; i += stride) {
            float4 x = x4[i], z = z4[i];
            gate_s += fmaxf(x.x, 0.f) - x.x * z.x + log1pf(expf(-fabsf(x.x)));
            gate_s += fmaxf(x.y, 0.f) - x.y * z.y + log1pf(expf(-fabsf(x.y)));
            gate_s += fmaxf(x.z, 0.f) - x.z * z.z + log1pf(expf(-fabsf(x.z)));
            gate_s += fmaxf(x.w, 0.f) - x.w * z.w + log1pf(expf(-fabsf(x.w)));
        }
    }

    if (wv < AWAVES) {
        // ---- Mel L1: wave owns 320 consecutive float4 per stream, depth-2 trio pipeline ----
        {
            const float4* a4 = (const float4*)mel_out;
            const float4* p4 = (const float4*)mel_post;
            const float4* t4 = (const float4*)mel_tgt;
            const int base = wv * MEL4PW + lane;
            float4 A0 = a4[base], P0 = p4[base], T0 = t4[base];
            #pragma unroll
            for (int s = 0; s < 5; ++s) {
                float4 A1, P1, T1;
                if (s < 4) {
                    const int i = base + (s + 1) * 64;
                    A1 = a4[i]; P1 = p4[i]; T1 = t4[i];
                }
                mel_s += fabsf(A0.x - T0.x) + fabsf(A0.y - T0.y) + fabsf(A0.z - T0.z) + fabsf(A0.w - T0.w);
                mel_s += fabsf(P0.x - T0.x) + fabsf(P0.y - T0.y) + fabsf(P0.z - T0.z) + fabsf(P0.w - T0.w);
                if (s < 4) { A0 = A1; P0 = P1; T0 = T1; }
            }
        }

        // ---- Alignment terms: wave owns 16 consecutive rows of one batch b.
        //      25 wave-loads of 1KB through an 8-deep ring -> ~8KB always in flight.
        //      Row/j decode per step is compile-time-constant arithmetic (<=1 row crossing). ----
        {
            const int b      = wv / WPB;                 // wave-uniform
            const int within = wv - b * WPB;
            const float fi0  = (float)(within * RPW);    // first row index of this wave
            const float ilf  = s_ilf[b];
            const float olf  = s_olf[b];
            const float sc   = s_sc[b];
            const float4* basep = ((const float4*)align)
                                + (size_t)(b * Tout + within * RPW) * TIN4;
            const float lf = (float)lane;

            float4 buf[8];
            #pragma unroll
            for (int s = 0; s < 8; ++s)
                buf[s] = basep[s * 64 + lane];

            #pragma unroll
            for (int s = 0; s < 25; ++s) {
                float4 a = buf[s & 7];
                if (s + 8 < 25)
                    buf[s & 7] = basep[(s + 8) * 64 + lane];

                // flat f = s*64 + lane covers rows q / q+1 (crossing at lane c)
                const int   q    = (64 * s) / 100;
                const int   c    = 100 * (q + 1) - 64 * s;   // lanes >= c are in row q+1
                const float self = (c < 64 && lane >= c) ? 1.0f : 0.0f;
                const float fr   = fi0 + (float)q + self;    // row index i (exact in fp32)
                const float jb   = 4.0f * lf + (float)(256 * s - 400 * q) - 400.0f * self;
                const bool  rv   = fr < olf;                 // i < output_len[b]

                const float av[4] = {a.x, a.y, a.z, a.w};
                #pragma unroll
                for (int k = 0; k < 4; ++k) {
                    const float jf = jb + (float)k;
                    att_s += (jf < fr) ? av[k] : 0.0f;       // j < i (strict)
                    const float d = fmaf(-jf, sc, fr);       // i - j*ol/il
                    const float e = exp2f(d * d * NEG_C);
                    const float g = fmaf(-av[k], e, av[k]);  // a*(1-e)
                    ga_s += (rv && (jf < ilf)) ? g : 0.0f;   // j < input_len[b]
                }
            }
        }
    }

    // ---- Block reduction: wave shuffle -> LDS -> one partial write per block ----
    __shared__ float smem[NTHR / 64][4];
    const int wid = threadIdx.x >> 6;

    mel_s  = wave_reduce(mel_s);
    gate_s = wave_reduce(gate_s);
    att_s  = wave_reduce(att_s);
    ga_s   = wave_reduce(ga_s);
    if (lane == 0) {
        smem[wid][0] = mel_s;
        smem[wid][1] = gate_s;
        smem[wid][2] = att_s;
        smem[wid][3] = ga_s;
    }
    __syncthreads();
    if (threadIdx.x == 0) {
        float m = 0.f, g = 0.f, at = 0.f, ga = 0.f;
        #pragma unroll
        for (int w = 0; w < NTHR / 64; ++w) {
            m  += smem[w][0];
            g  += smem[w][1];
            at += smem[w][2];
            ga += smem[w][3];
        }
        partials[blockIdx.x] = make_float4(m, g, at, ga);
    }
}

__global__ __launch_bounds__(512) void loss_final(
    const float4* __restrict__ partials, float* __restrict__ out)
{
    double m = 0.0, g = 0.0, at = 0.0, ga = 0.0;
    for (int i = threadIdx.x; i < NBLK; i += 512) {
        float4 p = partials[i];
        m += p.x; g += p.y; at += p.z; ga += p.w;
    }
    m  = wave_reduce_d(m);
    g  = wave_reduce_d(g);
    at = wave_reduce_d(at);
    ga = wave_reduce_d(ga);

    __shared__ double smem[8][4];
    const int lane = threadIdx.x & 63;
    const int wid  = threadIdx.x >> 6;
    if (lane == 0) {
        smem[wid][0] = m; smem[wid][1] = g; smem[wid][2] = at; smem[wid][3] = ga;
    }
    __syncthreads();
    if (threadIdx.x == 0) {
        double ms = 0, gs = 0, ats = 0, gas = 0;
        #pragma unroll
        for (int w = 0; w < 8; ++w) {
            ms += smem[w][0]; gs += smem[w][1]; ats += smem[w][2]; gas += smem[w][3];
        }
        const double mel  = ms  / (double)MEL_N;
        const double gate = gs  / (double)GATE_N;
        const double att  = ats / (double)Bsz;
        const double gav  = gas / (double)Bsz;
        const double total = mel + gate + (double)ATT_W * att + (double)GA_W * gav;
        out[0] = (float)total;
        out[1] = (float)mel;
        out[2] = (float)gate;
        out[3] = (float)att;
        out[4] = (float)gav;
    }
}

extern "C" void kernel_launch(void* const* d_in, const int* in_sizes, int n_in,
                              void* d_out, int out_size, void* d_ws, size_t ws_size,
                              hipStream_t stream) {
    const float* mel_out  = (const float*)d_in[0];
    const float* mel_post = (const float*)d_in[1];
    const float* gate_out = (const float*)d_in[2];
    const float* align    = (const float*)d_in[3];
    const float* mel_tgt  = (const float*)d_in[4];
    const float* gate_tgt = (const float*)d_in[5];
    const int*   in_len   = (const int*)d_in[6];
    const int*   out_len  = (const int*)d_in[7];

    float4* partials = (float4*)d_ws;       // NBLK * 16 B = 32 KiB; every block overwrites its slot

    loss_main<<<NBLK, NTHR, 0, stream>>>(mel_out, mel_post, gate_out, align,
                                         mel_tgt, gate_tgt, in_len, out_len, partials);
    loss_final<<<1, 512, 0, stream>>>(partials, (float*)d_out);
}

// Round 5
// 343.434 us; speedup vs baseline: 1.1051x; 1.1051x over previous
//
#include <hip/hip_runtime.h>
#include <math.h>

// Problem constants (fixed by setup_inputs)
constexpr int Bsz   = 64;
constexpr int Mmel  = 80;
constexpr int Tout  = 2000;
constexpr int Tin   = 400;
constexpr int MEL_N  = Bsz * Mmel * Tout;   // 10,240,000
constexpr int GATE_N = Bsz * Tout;          // 128,000
constexpr int ROWS   = Bsz * Tout;          // 128,000 alignment rows
constexpr int TIN4   = Tin / 4;             // 100 float4 per row

constexpr float ATT_W = 0.1f;
constexpr float GA_W  = 0.1f;
// exp(-d^2 * 3.125) == exp2(d^2 * -3.125*log2(e))
constexpr float NEG_C = -3.125f * 1.44269504088896340736f;

constexpr int NBLK   = 2048;                // 8 blocks/CU, single residency batch
constexpr int NTHR   = 256;
constexpr int NWAVES = NBLK * NTHR / 64;    // 8192

// clang ext-vector so __builtin_nontemporal_load applies cleanly
typedef float f4 __attribute__((ext_vector_type(4)));

__device__ __forceinline__ f4 ldnt(const f4* p) {
    return __builtin_nontemporal_load(p);
}

__device__ __forceinline__ float wave_reduce(float v) {
    #pragma unroll
    for (int off = 32; off > 0; off >>= 1)
        v += __shfl_down(v, off, 64);
    return v;
}

__device__ __forceinline__ double wave_reduce_d(double v) {
    #pragma unroll
    for (int off = 32; off > 0; off >>= 1)
        v += __shfl_down(v, off, 64);
    return v;
}

// Process one float4 of an alignment row. All-float compares (values integral,
// exact in fp32). Zeroed tail lanes contribute 0 to att; ga mask false there.
__device__ __forceinline__ void proc4(f4 a, float jb, float fi,
                                      float ilf, float olf, float sc,
                                      float& att_s, float& ga_s)
{
    const bool rv = fi < olf;               // irow < output_len
    const float av[4] = {a.x, a.y, a.z, a.w};
    #pragma unroll
    for (int k = 0; k < 4; ++k) {
        const float jf = jb + (float)k;
        att_s += (jf < fi) ? av[k] : 0.0f;  // jj < irow (strict)
        const float d = fmaf(-jf, sc, fi);  // fi - jf*scale
        const float e = exp2f(d * d * NEG_C);
        const float g = fmaf(-av[k], e, av[k]);   // av*(1-e)
        ga_s += (rv && (jf < ilf)) ? g : 0.0f;
    }
}

__global__ __launch_bounds__(NTHR) void loss_main(
    const float* __restrict__ mel_out,
    const float* __restrict__ mel_post,
    const float* __restrict__ gate_out,
    const float* __restrict__ align,
    const float* __restrict__ mel_tgt,
    const float* __restrict__ gate_tgt,
    const int*   __restrict__ in_len,
    const int*   __restrict__ out_len,
    float4* __restrict__ partials)          // partials[blockIdx] = {mel, gate, att, ga}
{
    __shared__ float s_ilf[Bsz];
    __shared__ float s_olf[Bsz];
    __shared__ float s_sc[Bsz];
    if (threadIdx.x < Bsz) {
        const float il = (float)in_len[threadIdx.x];
        const float ol = (float)out_len[threadIdx.x];
        s_ilf[threadIdx.x] = il;
        s_olf[threadIdx.x] = ol;
        s_sc[threadIdx.x]  = ol / il;
    }
    __syncthreads();

    const int tid    = blockIdx.x * blockDim.x + threadIdx.x;
    const int stride = gridDim.x * blockDim.x;   // 524,288

    float mel_s = 0.f, gate_s = 0.f, att_s = 0.f, ga_s = 0.f;

    // ---- Mel L1 (decoder + postnet), unroll x2, non-temporal ----
    {
        const f4* a4 = (const f4*)mel_out;
        const f4* p4 = (const f4*)mel_post;
        const f4* t4 = (const f4*)mel_tgt;
        const int n4 = MEL_N / 4;                // 2,560,000
        int i = tid;
        for (; i + stride < n4; i += 2 * stride) {
            const int i1 = i + stride;
            f4 a0 = ldnt(a4 + i),  a1 = ldnt(a4 + i1);
            f4 p0 = ldnt(p4 + i),  p1 = ldnt(p4 + i1);
            f4 t0 = ldnt(t4 + i),  t1 = ldnt(t4 + i1);
            mel_s += fabsf(a0.x - t0.x) + fabsf(a0.y - t0.y) + fabsf(a0.z - t0.z) + fabsf(a0.w - t0.w);
            mel_s += fabsf(p0.x - t0.x) + fabsf(p0.y - t0.y) + fabsf(p0.z - t0.z) + fabsf(p0.w - t0.w);
            mel_s += fabsf(a1.x - t1.x) + fabsf(a1.y - t1.y) + fabsf(a1.z - t1.z) + fabsf(a1.w - t1.w);
            mel_s += fabsf(p1.x - t1.x) + fabsf(p1.y - t1.y) + fabsf(p1.z - t1.z) + fabsf(p1.w - t1.w);
        }
        for (; i < n4; i += stride) {
            f4 a = ldnt(a4 + i), p = ldnt(p4 + i), t = ldnt(t4 + i);
            mel_s += fabsf(a.x - t.x) + fabsf(a.y - t.y) + fabsf(a.z - t.z) + fabsf(a.w - t.w);
            mel_s += fabsf(p.x - t.x) + fabsf(p.y - t.y) + fabsf(p.z - t.z) + fabsf(p.w - t.w);
        }
    }

    // ---- Gate BCE-with-logits (tiny; normal loads) ----
    {
        const float4* x4 = (const float4*)gate_out;
        const float4* z4 = (const float4*)gate_tgt;
        const int n4 = GATE_N / 4;
        for (int i = tid; i < n4; i += stride) {
            float4 x = x4[i], z = z4[i];
            gate_s += fmaxf(x.x, 0.f) - x.x * z.x + log1pf(expf(-fabsf(x.x)));
            gate_s += fmaxf(x.y, 0.f) - x.y * z.y + log1pf(expf(-fabsf(x.y)));
            gate_s += fmaxf(x.z, 0.f) - x.z * z.z + log1pf(expf(-fabsf(x.z)));
            gate_s += fmaxf(x.w, 0.f) - x.w * z.w + log1pf(expf(-fabsf(x.w)));
        }
    }

    // ---- Alignment terms: one 1600B row per wave per step, unroll x2 rows,
    //      non-temporal loads ----
    {
        const f4* al4 = (const f4*)align;
        const int wv   = (blockIdx.x << 2) | (threadIdx.x >> 6);   // 0..8191
        const int lane = threadIdx.x & 63;
        const float jb0 = (float)(4 * lane);
        const float jb1 = jb0 + 256.0f;
        const bool tail = lane < (TIN4 - 64);                      // lane < 36

        int r = wv;
        for (; r + NWAVES < ROWS; r += 2 * NWAVES) {
            const int r1 = r + NWAVES;
            const int b0 = r  / Tout;
            const int b1 = r1 / Tout;
            const int ir0 = r  - b0 * Tout;
            const int ir1 = r1 - b1 * Tout;
            const f4* rp0 = al4 + (size_t)r  * TIN4;
            const f4* rp1 = al4 + (size_t)r1 * TIN4;
            // 4 loads issued before any consume
            f4 a00 = ldnt(rp0 + lane);
            f4 a10 = ldnt(rp1 + lane);
            f4 a01 = {0.f, 0.f, 0.f, 0.f};
            f4 a11 = {0.f, 0.f, 0.f, 0.f};
            if (tail) a01 = ldnt(rp0 + lane + 64);
            if (tail) a11 = ldnt(rp1 + lane + 64);

            const float fi0 = (float)ir0, fi1 = (float)ir1;
            const float il0 = s_ilf[b0], ol0 = s_olf[b0], sc0 = s_sc[b0];
            const float il1 = s_ilf[b1], ol1 = s_olf[b1], sc1 = s_sc[b1];

            proc4(a00, jb0, fi0, il0, ol0, sc0, att_s, ga_s);
            proc4(a01, jb1, fi0, il0, ol0, sc0, att_s, ga_s);
            proc4(a10, jb0, fi1, il1, ol1, sc1, att_s, ga_s);
            proc4(a11, jb1, fi1, il1, ol1, sc1, att_s, ga_s);
        }
        for (; r < ROWS; r += NWAVES) {
            const int b  = r / Tout;
            const int ir = r - b * Tout;
            const f4* rp = al4 + (size_t)r * TIN4;
            f4 a0 = ldnt(rp + lane);
            f4 a1 = {0.f, 0.f, 0.f, 0.f};
            if (tail) a1 = ldnt(rp + lane + 64);
            const float fi = (float)ir;
            proc4(a0, jb0, fi, s_ilf[b], s_olf[b], s_sc[b], att_s, ga_s);
            proc4(a1, jb1, fi, s_ilf[b], s_olf[b], s_sc[b], att_s, ga_s);
        }
    }

    // ---- Block reduction: wave shuffle -> LDS -> one partial write per block ----
    __shared__ float smem[NTHR / 64][4];
    const int lane = threadIdx.x & 63;
    const int wid  = threadIdx.x >> 6;

    mel_s  = wave_reduce(mel_s);
    gate_s = wave_reduce(gate_s);
    att_s  = wave_reduce(att_s);
    ga_s   = wave_reduce(ga_s);
    if (lane == 0) {
        smem[wid][0] = mel_s;
        smem[wid][1] = gate_s;
        smem[wid][2] = att_s;
        smem[wid][3] = ga_s;
    }
    __syncthreads();
    if (threadIdx.x == 0) {
        float m = 0.f, g = 0.f, at = 0.f, ga = 0.f;
        #pragma unroll
        for (int w = 0; w < NTHR / 64; ++w) {
            m  += smem[w][0];
            g  += smem[w][1];
            at += smem[w][2];
            ga += smem[w][3];
        }
        partials[blockIdx.x] = make_float4(m, g, at, ga);
    }
}

__global__ __launch_bounds__(512) void loss_final(
    const float4* __restrict__ partials, float* __restrict__ out)
{
    double m = 0.0, g = 0.0, at = 0.0, ga = 0.0;
    for (int i = threadIdx.x; i < NBLK; i += 512) {
        float4 p = partials[i];
        m += p.x; g += p.y; at += p.z; ga += p.w;
    }
    m  = wave_reduce_d(m);
    g  = wave_reduce_d(g);
    at = wave_reduce_d(at);
    ga = wave_reduce_d(ga);

    __shared__ double smem[8][4];
    const int lane = threadIdx.x & 63;
    const int wid  = threadIdx.x >> 6;
    if (lane == 0) {
        smem[wid][0] = m; smem[wid][1] = g; smem[wid][2] = at; smem[wid][3] = ga;
    }
    __syncthreads();
    if (threadIdx.x == 0) {
        double ms = 0, gs = 0, ats = 0, gas = 0;
        #pragma unroll
        for (int w = 0; w < 8; ++w) {
            ms += smem[w][0]; gs += smem[w][1]; ats += smem[w][2]; gas += smem[w][3];
        }
        const double mel  = ms  / (double)MEL_N;
        const double gate = gs  / (double)GATE_N;
        const double att  = ats / (double)Bsz;
        const double gav  = gas / (double)Bsz;
        const double total = mel + gate + (double)ATT_W * att + (double)GA_W * gav;
        out[0] = (float)total;
        out[1] = (float)mel;
        out[2] = (float)gate;
        out[3] = (float)att;
        out[4] = (float)gav;
    }
}

extern "C" void kernel_launch(void* const* d_in, const int* in_sizes, int n_in,
                              void* d_out, int out_size, void* d_ws, size_t ws_size,
                              hipStream_t stream) {
    const float* mel_out  = (const float*)d_in[0];
    const float* mel_post = (const float*)d_in[1];
    const float* gate_out = (const float*)d_in[2];
    const float* align    = (const float*)d_in[3];
    const float* mel_tgt  = (const float*)d_in[4];
    const float* gate_tgt = (const float*)d_in[5];
    const int*   in_len   = (const int*)d_in[6];
    const int*   out_len  = (const int*)d_in[7];

    float4* partials = (float4*)d_ws;       // NBLK * 16 B = 32 KiB; every block overwrites its slot

    loss_main<<<NBLK, NTHR, 0, stream>>>(mel_out, mel_post, gate_out, align,
                                         mel_tgt, gate_tgt, in_len, out_len, partials);
    loss_final<<<1, 512, 0, stream>>>(partials, (float*)d_out);
}